// Round 1
// baseline (748.030 us; speedup 1.0000x reference)
//
#include <hip/hip_runtime.h>
#include <hip/hip_bf16.h>
#include <stdint.h>

#define N_TOK 8192
#define DIN   1024
#define DOUT  1024
#define HID   1024
#define NE    8
#define CAP   0.8f   // 1 - EPS

typedef __attribute__((ext_vector_type(8))) short short8;
typedef __attribute__((ext_vector_type(4))) float floatx4;

__device__ __forceinline__ void async_load16(const void* g, void* l) {
  __builtin_amdgcn_global_load_lds(
      (const __attribute__((address_space(1))) void*)g,
      (__attribute__((address_space(3))) void*)l,
      16, 0, 0);
}

// ---------------------------------------------------------------------------
// Selector: logits = x @ Wsel + bsel ; softmax ; sparse weights (capped cumsum,
// gather-with-order per the reference's torch.gather semantics).
// One wave per token. Also emits x as bf16 for the MFMA GEMMs.
// ---------------------------------------------------------------------------
__global__ __launch_bounds__(256) void selector_kernel(
    const float* __restrict__ x, const float* __restrict__ Wsel,
    const float* __restrict__ bsel,
    __hip_bfloat16* __restrict__ x_bf, float* __restrict__ sw)
{
  const int lane = threadIdx.x & 63;
  const int wave = threadIdx.x >> 6;
  const int n = blockIdx.x * 4 + wave;
  const float* xr = x + (size_t)n * DIN;

  float acc[8];
#pragma unroll
  for (int e = 0; e < 8; e++) acc[e] = 0.f;

#pragma unroll
  for (int i = 0; i < 16; i++) {
    const int d = lane + i * 64;
    const float xv = xr[d];
    x_bf[(size_t)n * DIN + d] = __float2bfloat16(xv);
    const float4* wr = (const float4*)(Wsel + d * 8);
    const float4 wlo = wr[0], whi = wr[1];
    acc[0] += xv * wlo.x; acc[1] += xv * wlo.y;
    acc[2] += xv * wlo.z; acc[3] += xv * wlo.w;
    acc[4] += xv * whi.x; acc[5] += xv * whi.y;
    acc[6] += xv * whi.z; acc[7] += xv * whi.w;
  }
#pragma unroll
  for (int off = 32; off >= 1; off >>= 1)
#pragma unroll
    for (int e = 0; e < 8; e++) acc[e] += __shfl_xor(acc[e], off);

  if (lane == 0) {
    float w[8];
    float mx = -1e30f;
#pragma unroll
    for (int e = 0; e < 8; e++) { w[e] = acc[e] + bsel[e]; mx = fmaxf(mx, w[e]); }
    float s = 0.f;
#pragma unroll
    for (int e = 0; e < 8; e++) { w[e] = expf(w[e] - mx); s += w[e]; }
    const float inv = 1.f / s;
#pragma unroll
    for (int e = 0; e < 8; e++) w[e] *= inv;

    // stable descending argsort (insertion sort; strict < keeps ties stable)
    float wsrt[8]; int ord[8];
    for (int k = 0; k < 8; k++) {
      const float v = w[k];
      int j = k;
      while (j > 0 && wsrt[j - 1] < v) { wsrt[j] = wsrt[j - 1]; ord[j] = ord[j - 1]; j--; }
      wsrt[j] = v; ord[j] = k;
    }
    // capped cumulative sparse weights (sorted order)
    float cum = 0.f, sws[8];
    for (int k = 0; k < 8; k++) {
      cum += wsrt[k];
      const float capped = fminf(cum, CAP);
      sws[k] = fmaxf(capped - cum + wsrt[k], 0.f);
    }
    // faithful to torch.gather(sparse_weight, 1, index): sw[j] = sws[ord[j]]
    for (int j = 0; j < 8; j++) sw[(size_t)n * 8 + j] = sws[ord[j]];
  }
}

// ---------------------------------------------------------------------------
// W1[e][k][n] fp32 -> W1t[e][n][k] bf16 ; W2[e][h][o] fp32 -> W2t[e][o][h] bf16
// 32x32 LDS tile transpose. grid = (32, 32, 16): z = mat*8 + expert.
// ---------------------------------------------------------------------------
__global__ __launch_bounds__(256) void convert_weights_kernel(
    const float* __restrict__ W1, const float* __restrict__ W2,
    __hip_bfloat16* __restrict__ W1t, __hip_bfloat16* __restrict__ W2t)
{
  __shared__ float tile[32][33];
  const int z = blockIdx.z;
  const float* src = (z & 8) ? W2 : W1;
  __hip_bfloat16* dst = (z & 8) ? W2t : W1t;
  const int e = z & 7;
  src += (size_t)e * 1024 * 1024;
  dst += (size_t)e * 1024 * 1024;
  const int R = blockIdx.y * 32, C = blockIdx.x * 32;
  const int c = threadIdx.x & 31, r0 = threadIdx.x >> 5;
#pragma unroll
  for (int p = 0; p < 4; p++) {
    const int r = r0 + p * 8;
    tile[r][c] = src[(size_t)(R + r) * 1024 + C + c];
  }
  __syncthreads();
#pragma unroll
  for (int p = 0; p < 4; p++) {
    const int r = r0 + p * 8;
    dst[(size_t)(C + r) * 1024 + R + c] = __float2bfloat16(tile[c][r]);
  }
}

// ---------------------------------------------------------------------------
// 128x128x(BK=32) bf16 MFMA GEMM, m97 structure. A [M,K] rm, Bt [N,K] rm.
// MODE 0: Hout = bf16(relu(acc + bias))           (expert FC1)
// MODE 1: Out (+)= sw[m,e] * (acc + bias)         (expert FC2 + combine)
// ---------------------------------------------------------------------------
template <int MODE>
__global__ __launch_bounds__(256, 2) void gemm128(
    const __hip_bfloat16* __restrict__ A,
    const __hip_bfloat16* __restrict__ Bt,
    const float* __restrict__ bias,
    const float* __restrict__ sw, int e, int beta,
    __hip_bfloat16* __restrict__ Hout, float* __restrict__ Out,
    int K, int Nn)
{
  __shared__ __align__(16) __hip_bfloat16 sA[128 * 32];
  __shared__ __align__(16) __hip_bfloat16 sB[128 * 32];
  const int t = threadIdx.x;
  const int lane = t & 63;
  const int wave = t >> 6;
  const int wm = (wave & 1) * 64;
  const int wn = (wave >> 1) * 64;
  const int m0 = blockIdx.y * 128;
  const int n0 = blockIdx.x * 128;

  floatx4 acc[4][4];
#pragma unroll
  for (int i = 0; i < 4; i++)
#pragma unroll
    for (int j = 0; j < 4; j++) acc[i][j] = (floatx4){0.f, 0.f, 0.f, 0.f};

  // staging: thread t loads 16B; LDS dest = t*16 bytes (affine in lane) x2 rounds
  const int sr = t >> 2;
  const int sc = (t & 3) * 8;
  const __hip_bfloat16* Ag = A + (size_t)(m0 + sr) * K + sc;
  const __hip_bfloat16* Bg = Bt + (size_t)(n0 + sr) * K + sc;
  __hip_bfloat16* lA = &sA[sr * 32 + sc];
  __hip_bfloat16* lB = &sB[sr * 32 + sc];

  const int rf = lane & 15;
  const int k8 = (lane >> 4) * 8;
  const __hip_bfloat16* sAr = &sA[(wm + rf) * 32 + k8];
  const __hip_bfloat16* sBr = &sB[(wn + rf) * 32 + k8];

  for (int k0 = 0; k0 < K; k0 += 32) {
    async_load16(Ag + k0, lA);
    async_load16(Ag + (size_t)64 * K + k0, lA + 64 * 32);
    async_load16(Bg + k0, lB);
    async_load16(Bg + (size_t)64 * K + k0, lB + 64 * 32);
    __syncthreads();  // drains vmcnt -> LDS tiles visible
    short8 aF[4], bF[4];
#pragma unroll
    for (int i = 0; i < 4; i++) aF[i] = *(const short8*)(sAr + i * 16 * 32);
#pragma unroll
    for (int j = 0; j < 4; j++) bF[j] = *(const short8*)(sBr + j * 16 * 32);
#pragma unroll
    for (int i = 0; i < 4; i++)
#pragma unroll
      for (int j = 0; j < 4; j++)
        acc[i][j] = __builtin_amdgcn_mfma_f32_16x16x32_bf16(aF[i], bF[j], acc[i][j], 0, 0, 0);
    __syncthreads();  // protect LDS from next stage
  }

  // epilogue: C/D layout col = lane&15, row = (lane>>4)*4 + reg
  const int quad = lane >> 4;
  const int cn = lane & 15;
#pragma unroll
  for (int i = 0; i < 4; i++) {
#pragma unroll
    for (int r = 0; r < 4; r++) {
      const int gm = m0 + wm + i * 16 + quad * 4 + r;
      float swv = 0.f;
      if (MODE == 1) swv = sw[gm * 8 + e];
#pragma unroll
      for (int j = 0; j < 4; j++) {
        const int gn = n0 + wn + j * 16 + cn;
        const float v = acc[i][j][r] + bias[gn];
        if (MODE == 0) {
          Hout[(size_t)gm * Nn + gn] = __float2bfloat16(fmaxf(v, 0.f));
        } else {
          const float o = swv * v;
          const size_t off = (size_t)gm * Nn + gn;
          if (beta) Out[off] += o; else Out[off] = o;
        }
      }
    }
  }
}

// ---------------------------------------------------------------------------
extern "C" void kernel_launch(void* const* d_in, const int* in_sizes, int n_in,
                              void* d_out, int out_size, void* d_ws, size_t ws_size,
                              hipStream_t stream) {
  const float* x    = (const float*)d_in[0];
  const float* Wsel = (const float*)d_in[1];
  const float* bsel = (const float*)d_in[2];
  const float* W1   = (const float*)d_in[3];
  const float* b1   = (const float*)d_in[4];
  const float* W2   = (const float*)d_in[5];
  const float* b2   = (const float*)d_in[6];
  float* out = (float*)d_out;

  char* ws = (char*)d_ws;
  __hip_bfloat16* x_bf = (__hip_bfloat16*)ws; ws += (size_t)N_TOK * DIN * 2;
  __hip_bfloat16* W1t  = (__hip_bfloat16*)ws; ws += (size_t)NE * DIN * HID * 2;
  __hip_bfloat16* W2t  = (__hip_bfloat16*)ws; ws += (size_t)NE * HID * DOUT * 2;
  __hip_bfloat16* hbuf = (__hip_bfloat16*)ws; ws += (size_t)N_TOK * HID * 2;
  float* sw            = (float*)ws;          ws += (size_t)N_TOK * NE * 4;

  selector_kernel<<<N_TOK / 4, 256, 0, stream>>>(x, Wsel, bsel, x_bf, sw);
  convert_weights_kernel<<<dim3(32, 32, 16), 256, 0, stream>>>(W1, W2, W1t, W2t);

  for (int e = 0; e < NE; e++) {
    gemm128<0><<<dim3(HID / 128, N_TOK / 128), 256, 0, stream>>>(
        x_bf, W1t + (size_t)e * DIN * HID, b1 + (size_t)e * HID,
        nullptr, e, 0, hbuf, nullptr, DIN, HID);
    gemm128<1><<<dim3(DOUT / 128, N_TOK / 128), 256, 0, stream>>>(
        hbuf, W2t + (size_t)e * HID * DOUT, b2 + (size_t)e * DOUT,
        sw, e, (e != 0), nullptr, out, HID, DOUT);
  }
}

// Round 2
// 422.630 us; speedup vs baseline: 1.7699x; 1.7699x over previous
//
#include <hip/hip_runtime.h>
#include <hip/hip_bf16.h>
#include <stdint.h>

#define N_TOK 8192
#define DIN   1024
#define DOUT  1024
#define HID   1024
#define NE    8
#define CAP   0.8f   // 1 - EPS

typedef __attribute__((ext_vector_type(8))) short short8;
typedef __attribute__((ext_vector_type(4))) float floatx4;

__device__ __forceinline__ void async_load16(const void* g, void* l) {
  __builtin_amdgcn_global_load_lds(
      (const __attribute__((address_space(1))) void*)g,
      (__attribute__((address_space(3))) void*)l,
      16, 0, 0);
}

// ---------------------------------------------------------------------------
// Zero-fill d_out (poisoned 0xAA each call) and the per-expert counters.
// ---------------------------------------------------------------------------
__global__ __launch_bounds__(256) void zero_kernel(float4* __restrict__ out4,
                                                   int n4, int* __restrict__ cnt) {
  const int stride = gridDim.x * 256;
  for (int i = blockIdx.x * 256 + threadIdx.x; i < n4; i += stride)
    out4[i] = (float4){0.f, 0.f, 0.f, 0.f};
  if (blockIdx.x == 0 && threadIdx.x < NE) cnt[threadIdx.x] = 0;
}

// ---------------------------------------------------------------------------
// Selector: logits = x @ Wsel + bsel ; softmax ; capped-cumsum sparse weights
// (gather-with-order per torch.gather semantics). Emits x as bf16, plus
// per-expert compaction lists (idx/cnt) for the sparse dispatch.
// ---------------------------------------------------------------------------
__global__ __launch_bounds__(256) void selector_kernel(
    const float* __restrict__ x, const float* __restrict__ Wsel,
    const float* __restrict__ bsel,
    __hip_bfloat16* __restrict__ x_bf, float* __restrict__ sw,
    int* __restrict__ idx, int* __restrict__ cnt)
{
  const int lane = threadIdx.x & 63;
  const int wave = threadIdx.x >> 6;
  const int n = blockIdx.x * 4 + wave;
  const float* xr = x + (size_t)n * DIN;

  float acc[8];
#pragma unroll
  for (int e = 0; e < 8; e++) acc[e] = 0.f;

#pragma unroll
  for (int i = 0; i < 16; i++) {
    const int d = lane + i * 64;
    const float xv = xr[d];
    x_bf[(size_t)n * DIN + d] = __float2bfloat16(xv);
    const float4* wr = (const float4*)(Wsel + d * 8);
    const float4 wlo = wr[0], whi = wr[1];
    acc[0] += xv * wlo.x; acc[1] += xv * wlo.y;
    acc[2] += xv * wlo.z; acc[3] += xv * wlo.w;
    acc[4] += xv * whi.x; acc[5] += xv * whi.y;
    acc[6] += xv * whi.z; acc[7] += xv * whi.w;
  }
#pragma unroll
  for (int off = 32; off >= 1; off >>= 1)
#pragma unroll
    for (int e = 0; e < 8; e++) acc[e] += __shfl_xor(acc[e], off);

  if (lane == 0) {
    float w[8];
    float mx = -1e30f;
#pragma unroll
    for (int e = 0; e < 8; e++) { w[e] = acc[e] + bsel[e]; mx = fmaxf(mx, w[e]); }
    float s = 0.f;
#pragma unroll
    for (int e = 0; e < 8; e++) { w[e] = expf(w[e] - mx); s += w[e]; }
    const float inv = 1.f / s;
#pragma unroll
    for (int e = 0; e < 8; e++) w[e] *= inv;

    // stable descending argsort (insertion sort; strict < keeps ties stable)
    float wsrt[8]; int ord[8];
    for (int k = 0; k < 8; k++) {
      const float v = w[k];
      int j = k;
      while (j > 0 && wsrt[j - 1] < v) { wsrt[j] = wsrt[j - 1]; ord[j] = ord[j - 1]; j--; }
      wsrt[j] = v; ord[j] = k;
    }
    // capped cumulative sparse weights (sorted order)
    float cum = 0.f, sws[8];
    for (int k = 0; k < 8; k++) {
      cum += wsrt[k];
      const float capped = fminf(cum, CAP);
      sws[k] = fmaxf(capped - cum + wsrt[k], 0.f);
    }
    // faithful to torch.gather(sparse_weight, 1, index): sw[j] = sws[ord[j]]
    float swl[8];
    for (int j = 0; j < 8; j++) swl[j] = sws[ord[j]];
    for (int j = 0; j < 8; j++) {
      sw[(size_t)n * 8 + j] = swl[j];
      if (swl[j] > 0.f) {                 // exact-zero contributions skipped
        const int pos = atomicAdd(&cnt[j], 1);
        idx[j * N_TOK + pos] = n;
      }
    }
  }
}

// ---------------------------------------------------------------------------
// W1[e][k][n] fp32 -> W1t[e][n][k] bf16 ; W2[e][h][o] fp32 -> W2t[e][o][h] bf16
// ---------------------------------------------------------------------------
__global__ __launch_bounds__(256) void convert_weights_kernel(
    const float* __restrict__ W1, const float* __restrict__ W2,
    __hip_bfloat16* __restrict__ W1t, __hip_bfloat16* __restrict__ W2t)
{
  __shared__ float tile[32][33];
  const int z = blockIdx.z;
  const float* src = (z & 8) ? W2 : W1;
  __hip_bfloat16* dst = (z & 8) ? W2t : W1t;
  const int e = z & 7;
  src += (size_t)e * 1024 * 1024;
  dst += (size_t)e * 1024 * 1024;
  const int R = blockIdx.y * 32, C = blockIdx.x * 32;
  const int c = threadIdx.x & 31, r0 = threadIdx.x >> 5;
#pragma unroll
  for (int p = 0; p < 4; p++) {
    const int r = r0 + p * 8;
    tile[r][c] = src[(size_t)(R + r) * 1024 + C + c];
  }
  __syncthreads();
#pragma unroll
  for (int p = 0; p < 4; p++) {
    const int r = r0 + p * 8;
    dst[(size_t)(C + r) * 1024 + R + c] = __float2bfloat16(tile[c][r]);
  }
}

// ---------------------------------------------------------------------------
// Compacted per-expert GEMM, m97 structure (128x128, BK=32), grid z = expert.
// MODE 0 (FC1): A = gather(x_bf, idx[e]);  hpool[e] = bf16(relu(A W1t^T + b1))
// MODE 1 (FC2): A = hpool[e];  out[idx[e][m]] += sw * (A W2t^T + b2)  (atomic)
// Row-blocks beyond cnt[e] exit immediately.
// ---------------------------------------------------------------------------
template <int MODE>
__global__ __launch_bounds__(256, 2) void moe_gemm(
    const __hip_bfloat16* __restrict__ x_bf,
    __hip_bfloat16* __restrict__ hpool,
    const __hip_bfloat16* __restrict__ Wt,
    const float* __restrict__ biasAll,
    const float* __restrict__ sw,
    const int* __restrict__ idx, const int* __restrict__ cnt,
    float* __restrict__ out)
{
  const int e = blockIdx.z;
  const int count = cnt[e];
  const int m0 = blockIdx.y * 128;
  if (m0 >= count) return;
  const int n0 = blockIdx.x * 128;

  __shared__ __align__(16) __hip_bfloat16 sA[128 * 32];
  __shared__ __align__(16) __hip_bfloat16 sB[128 * 32];
  const int t = threadIdx.x;
  const int lane = t & 63;
  const int wave = t >> 6;
  const int wm = (wave & 1) * 64;
  const int wn = (wave >> 1) * 64;
  const int* idx_e = idx + e * N_TOK;
  const float* bias = biasAll + e * 1024;

  floatx4 acc[4][4];
#pragma unroll
  for (int i = 0; i < 4; i++)
#pragma unroll
    for (int j = 0; j < 4; j++) acc[i][j] = (floatx4){0.f, 0.f, 0.f, 0.f};

  // staging addresses: thread t loads 16B for rows sr and sr+64
  const int sr = t >> 2;
  const int sc = (t & 3) * 8;
  const __hip_bfloat16* Ag0;
  const __hip_bfloat16* Ag1;
  if (MODE == 0) {
    const int t0 = idx_e[min(m0 + sr, count - 1)];       // clamp tail (valid rows)
    const int t1 = idx_e[min(m0 + sr + 64, count - 1)];
    Ag0 = x_bf + (size_t)t0 * 1024 + sc;
    Ag1 = x_bf + (size_t)t1 * 1024 + sc;
  } else {
    const __hip_bfloat16* hp = hpool + (size_t)e * N_TOK * 1024;
    Ag0 = hp + (size_t)(m0 + sr) * 1024 + sc;            // tail reads scratch: finite
    Ag1 = hp + (size_t)(m0 + sr + 64) * 1024 + sc;
  }
  const __hip_bfloat16* Bg = Wt + (size_t)e * 1024 * 1024 + (size_t)(n0 + sr) * 1024 + sc;
  __hip_bfloat16* lA = &sA[sr * 32 + sc];
  __hip_bfloat16* lB = &sB[sr * 32 + sc];

  const int rf = lane & 15;
  const int k8 = (lane >> 4) * 8;
  const __hip_bfloat16* sAr = &sA[(wm + rf) * 32 + k8];
  const __hip_bfloat16* sBr = &sB[(wn + rf) * 32 + k8];

  for (int k0 = 0; k0 < 1024; k0 += 32) {
    async_load16(Ag0 + k0, lA);
    async_load16(Ag1 + k0, lA + 64 * 32);
    async_load16(Bg + k0, lB);
    async_load16(Bg + (size_t)64 * 1024 + k0, lB + 64 * 32);
    __syncthreads();
    short8 aF[4], bF[4];
#pragma unroll
    for (int i = 0; i < 4; i++) aF[i] = *(const short8*)(sAr + i * 16 * 32);
#pragma unroll
    for (int j = 0; j < 4; j++) bF[j] = *(const short8*)(sBr + j * 16 * 32);
#pragma unroll
    for (int i = 0; i < 4; i++)
#pragma unroll
      for (int j = 0; j < 4; j++)
        acc[i][j] = __builtin_amdgcn_mfma_f32_16x16x32_bf16(aF[i], bF[j], acc[i][j], 0, 0, 0);
    __syncthreads();
  }

  // epilogue: C/D layout col = lane&15, row = (lane>>4)*4 + reg
  const int quad = lane >> 4;
  const int cn = lane & 15;
#pragma unroll
  for (int i = 0; i < 4; i++) {
#pragma unroll
    for (int r = 0; r < 4; r++) {
      const int gm = m0 + wm + i * 16 + quad * 4 + r;
      if (gm >= count) continue;
      int tok = 0; float swv = 0.f;
      if (MODE == 1) {
        tok = idx_e[gm];
        swv = sw[tok * 8 + e];
      }
#pragma unroll
      for (int j = 0; j < 4; j++) {
        const int gn = n0 + wn + j * 16 + cn;
        const float v = acc[i][j][r] + bias[gn];
        if (MODE == 0) {
          hpool[((size_t)e * N_TOK + gm) * 1024 + gn] = __float2bfloat16(fmaxf(v, 0.f));
        } else {
          unsafeAtomicAdd(&out[(size_t)tok * 1024 + gn], swv * v);
        }
      }
    }
  }
}

// ---------------------------------------------------------------------------
// Dense fallback GEMM (round-1 verified) — used only if ws_size is too small
// for the compacted h-pool.
// ---------------------------------------------------------------------------
template <int MODE>
__global__ __launch_bounds__(256, 2) void gemm128(
    const __hip_bfloat16* __restrict__ A,
    const __hip_bfloat16* __restrict__ Bt,
    const float* __restrict__ bias,
    const float* __restrict__ sw, int e, int beta,
    __hip_bfloat16* __restrict__ Hout, float* __restrict__ Out,
    int K, int Nn)
{
  __shared__ __align__(16) __hip_bfloat16 sA[128 * 32];
  __shared__ __align__(16) __hip_bfloat16 sB[128 * 32];
  const int t = threadIdx.x;
  const int lane = t & 63;
  const int wave = t >> 6;
  const int wm = (wave & 1) * 64;
  const int wn = (wave >> 1) * 64;
  const int m0 = blockIdx.y * 128;
  const int n0 = blockIdx.x * 128;

  floatx4 acc[4][4];
#pragma unroll
  for (int i = 0; i < 4; i++)
#pragma unroll
    for (int j = 0; j < 4; j++) acc[i][j] = (floatx4){0.f, 0.f, 0.f, 0.f};

  const int sr = t >> 2;
  const int sc = (t & 3) * 8;
  const __hip_bfloat16* Ag = A + (size_t)(m0 + sr) * K + sc;
  const __hip_bfloat16* Bg = Bt + (size_t)(n0 + sr) * K + sc;
  __hip_bfloat16* lA = &sA[sr * 32 + sc];
  __hip_bfloat16* lB = &sB[sr * 32 + sc];

  const int rf = lane & 15;
  const int k8 = (lane >> 4) * 8;
  const __hip_bfloat16* sAr = &sA[(wm + rf) * 32 + k8];
  const __hip_bfloat16* sBr = &sB[(wn + rf) * 32 + k8];

  for (int k0 = 0; k0 < K; k0 += 32) {
    async_load16(Ag + k0, lA);
    async_load16(Ag + (size_t)64 * K + k0, lA + 64 * 32);
    async_load16(Bg + k0, lB);
    async_load16(Bg + (size_t)64 * K + k0, lB + 64 * 32);
    __syncthreads();
    short8 aF[4], bF[4];
#pragma unroll
    for (int i = 0; i < 4; i++) aF[i] = *(const short8*)(sAr + i * 16 * 32);
#pragma unroll
    for (int j = 0; j < 4; j++) bF[j] = *(const short8*)(sBr + j * 16 * 32);
#pragma unroll
    for (int i = 0; i < 4; i++)
#pragma unroll
      for (int j = 0; j < 4; j++)
        acc[i][j] = __builtin_amdgcn_mfma_f32_16x16x32_bf16(aF[i], bF[j], acc[i][j], 0, 0, 0);
    __syncthreads();
  }

  const int quad = lane >> 4;
  const int cn = lane & 15;
#pragma unroll
  for (int i = 0; i < 4; i++) {
#pragma unroll
    for (int r = 0; r < 4; r++) {
      const int gm = m0 + wm + i * 16 + quad * 4 + r;
      float swv = 0.f;
      if (MODE == 1) swv = sw[gm * 8 + e];
#pragma unroll
      for (int j = 0; j < 4; j++) {
        const int gn = n0 + wn + j * 16 + cn;
        const float v = acc[i][j][r] + bias[gn];
        if (MODE == 0) {
          Hout[(size_t)gm * Nn + gn] = __float2bfloat16(fmaxf(v, 0.f));
        } else {
          const float o = swv * v;
          const size_t off = (size_t)gm * Nn + gn;
          if (beta) Out[off] += o; else Out[off] = o;
        }
      }
    }
  }
}

// ---------------------------------------------------------------------------
extern "C" void kernel_launch(void* const* d_in, const int* in_sizes, int n_in,
                              void* d_out, int out_size, void* d_ws, size_t ws_size,
                              hipStream_t stream) {
  const float* x    = (const float*)d_in[0];
  const float* Wsel = (const float*)d_in[1];
  const float* bsel = (const float*)d_in[2];
  const float* W1   = (const float*)d_in[3];
  const float* b1   = (const float*)d_in[4];
  const float* W2   = (const float*)d_in[5];
  const float* b2   = (const float*)d_in[6];
  float* out = (float*)d_out;

  char* ws = (char*)d_ws;
  __hip_bfloat16* x_bf = (__hip_bfloat16*)ws; ws += (size_t)N_TOK * DIN * 2;
  __hip_bfloat16* W1t  = (__hip_bfloat16*)ws; ws += (size_t)NE * DIN * HID * 2;
  __hip_bfloat16* W2t  = (__hip_bfloat16*)ws; ws += (size_t)NE * HID * DOUT * 2;
  float* sw            = (float*)ws;          ws += (size_t)N_TOK * NE * 4;
  int* idx             = (int*)ws;            ws += (size_t)NE * N_TOK * 4;
  int* cnt             = (int*)ws;            ws += 256;
  __hip_bfloat16* hpool = (__hip_bfloat16*)ws;  // sparse: NE*N_TOK*HID*2 = 134 MB
  const size_t need_sparse = (size_t)(ws - (char*)d_ws) + (size_t)NE * N_TOK * HID * 2;
  const size_t need_dense  = (size_t)(ws - (char*)d_ws) + (size_t)N_TOK * HID * 2;
  const bool sparse_ok = ws_size >= need_sparse;

  zero_kernel<<<1024, 256, 0, stream>>>((float4*)out, N_TOK * DOUT / 4, cnt);
  selector_kernel<<<N_TOK / 4, 256, 0, stream>>>(x, Wsel, bsel, x_bf, sw, idx, cnt);
  convert_weights_kernel<<<dim3(32, 32, 16), 256, 0, stream>>>(W1, W2, W1t, W2t);

  if (sparse_ok) {
    moe_gemm<0><<<dim3(HID / 128, N_TOK / 128, NE), 256, 0, stream>>>(
        x_bf, hpool, W1t, b1, sw, idx, cnt, out);
    moe_gemm<1><<<dim3(DOUT / 128, N_TOK / 128, NE), 256, 0, stream>>>(
        x_bf, hpool, W2t, b2, sw, idx, cnt, out);
  } else if (ws_size >= need_dense) {
    __hip_bfloat16* hbuf = hpool;  // only N_TOK*HID*2 here
    for (int e = 0; e < NE; e++) {
      gemm128<0><<<dim3(HID / 128, N_TOK / 128), 256, 0, stream>>>(
          x_bf, W1t + (size_t)e * DIN * HID, b1 + (size_t)e * HID,
          nullptr, e, 0, hbuf, nullptr, DIN, HID);
      gemm128<1><<<dim3(DOUT / 128, N_TOK / 128), 256, 0, stream>>>(
          hbuf, W2t + (size_t)e * HID * DOUT, b2 + (size_t)e * DOUT,
          sw, e, (e != 0), nullptr, out, HID, DOUT);
    }
  }
}

// Round 4
// 321.610 us; speedup vs baseline: 2.3259x; 1.3141x over previous
//
#include <hip/hip_runtime.h>
#include <hip/hip_bf16.h>
#include <stdint.h>

#define N_TOK 8192
#define DIN   1024
#define DOUT  1024
#define HID   1024
#define NE    8
#define CAP   0.8f   // 1 - EPS

typedef __attribute__((ext_vector_type(8))) short short8;
typedef __attribute__((ext_vector_type(4))) float floatx4;

__device__ __forceinline__ void async_load16(const void* g, void* l) {
  __builtin_amdgcn_global_load_lds(
      (const __attribute__((address_space(1))) void*)g,
      (__attribute__((address_space(3))) void*)l,
      16, 0, 0);
}

__device__ __forceinline__ unsigned short bf16_bits(float f) {
  return __builtin_bit_cast(unsigned short, __float2bfloat16(f));
}

// ---------------------------------------------------------------------------
// Zero-fill d_out (poisoned 0xAA each call).
// ---------------------------------------------------------------------------
__global__ __launch_bounds__(256) void zero_kernel(float4* __restrict__ out4, int n4) {
  const int stride = gridDim.x * 256;
  for (int i = blockIdx.x * 256 + threadIdx.x; i < n4; i += stride)
    out4[i] = (float4){0.f, 0.f, 0.f, 0.f};
}

// ---------------------------------------------------------------------------
// Selector: logits = x @ Wsel + bsel ; softmax ; capped-cumsum sparse weights
// (gather-with-order per torch.gather semantics). Emits x as bf16 + sw.
// NO atomics here (round-2 lesson: 65k returning atomics on one cache line
// serialized the whole kernel at 155 us). Compaction is a separate kernel.
// ---------------------------------------------------------------------------
__global__ __launch_bounds__(256) void selector_kernel(
    const float* __restrict__ x, const float* __restrict__ Wsel,
    const float* __restrict__ bsel,
    __hip_bfloat16* __restrict__ x_bf, float* __restrict__ sw)
{
  const int lane = threadIdx.x & 63;
  const int wave = threadIdx.x >> 6;
  const int n = blockIdx.x * 4 + wave;
  const float4* xr4 = (const float4*)(x + (size_t)n * DIN);
  ushort4* xb4 = (ushort4*)(x_bf + (size_t)n * DIN);

  float acc[8];
#pragma unroll
  for (int e = 0; e < 8; e++) acc[e] = 0.f;

#pragma unroll
  for (int i = 0; i < 4; i++) {
    const int d4 = lane + i * 64;          // float4 index; covers dims 4*d4..4*d4+3
    const float4 xv = xr4[d4];
    ushort4 p;
    p.x = bf16_bits(xv.x);
    p.y = bf16_bits(xv.y);
    p.z = bf16_bits(xv.z);
    p.w = bf16_bits(xv.w);
    xb4[d4] = p;
    const float xs[4] = {xv.x, xv.y, xv.z, xv.w};
#pragma unroll
    for (int q = 0; q < 4; q++) {
      const int d = d4 * 4 + q;
      const float4* wr = (const float4*)(Wsel + d * 8);
      const float4 wlo = wr[0], whi = wr[1];
      const float xv1 = xs[q];
      acc[0] += xv1 * wlo.x; acc[1] += xv1 * wlo.y;
      acc[2] += xv1 * wlo.z; acc[3] += xv1 * wlo.w;
      acc[4] += xv1 * whi.x; acc[5] += xv1 * whi.y;
      acc[6] += xv1 * whi.z; acc[7] += xv1 * whi.w;
    }
  }
#pragma unroll
  for (int off = 32; off >= 1; off >>= 1)
#pragma unroll
    for (int e = 0; e < 8; e++) acc[e] += __shfl_xor(acc[e], off);

  if (lane == 0) {
    float w[8];
    float mx = -1e30f;
#pragma unroll
    for (int e = 0; e < 8; e++) { w[e] = acc[e] + bsel[e]; mx = fmaxf(mx, w[e]); }
    float s = 0.f;
#pragma unroll
    for (int e = 0; e < 8; e++) { w[e] = expf(w[e] - mx); s += w[e]; }
    const float inv = 1.f / s;
#pragma unroll
    for (int e = 0; e < 8; e++) w[e] *= inv;

    // stable descending argsort (insertion sort; strict < keeps ties stable)
    float wsrt[8]; int ord[8];
    for (int k = 0; k < 8; k++) {
      const float v = w[k];
      int j = k;
      while (j > 0 && wsrt[j - 1] < v) { wsrt[j] = wsrt[j - 1]; ord[j] = ord[j - 1]; j--; }
      wsrt[j] = v; ord[j] = k;
    }
    // capped cumulative sparse weights (sorted order)
    float cum = 0.f, sws[8];
    for (int k = 0; k < 8; k++) {
      cum += wsrt[k];
      const float capped = fminf(cum, CAP);
      sws[k] = fmaxf(capped - cum + wsrt[k], 0.f);
    }
    // faithful to torch.gather(sparse_weight, 1, index): sw[j] = sws[ord[j]]
    for (int j = 0; j < 8; j++) sw[(size_t)n * 8 + j] = sws[ord[j]];
  }
}

// ---------------------------------------------------------------------------
// Per-expert token compaction with ZERO global atomics.
// grid = NE blocks; 1024 threads = 16 waves; 8 chunks of 1024 tokens.
// ballot -> wave popcount -> LDS scan over 16 waves -> ordered compaction.
// ---------------------------------------------------------------------------
__global__ __launch_bounds__(1024) void compact_kernel(
    const float* __restrict__ sw, int* __restrict__ idx, int* __restrict__ cnt)
{
  const int e = blockIdx.x;
  const int t = threadIdx.x;
  const int lane = t & 63;
  const int wv = t >> 6;
  __shared__ int wave_base[16];
  __shared__ int chunk_total;
  int base = 0;
#pragma unroll
  for (int c = 0; c < 8; c++) {
    const int tok = c * 1024 + t;
    const bool act = sw[(size_t)tok * 8 + e] > 0.f;
    const unsigned long long m = __ballot(act);
    const int before = __popcll(m & ((1ull << lane) - 1ull));
    if (lane == 0) wave_base[wv] = __popcll(m);
    __syncthreads();
    if (t == 0) {
      int s = 0;
      for (int w = 0; w < 16; w++) { const int v = wave_base[w]; wave_base[w] = s; s += v; }
      chunk_total = s;
    }
    __syncthreads();
    if (act) idx[e * N_TOK + base + wave_base[wv] + before] = tok;
    base += chunk_total;
    __syncthreads();   // protect wave_base/chunk_total before next chunk
  }
  if (t == 0) cnt[e] = base;
}

// ---------------------------------------------------------------------------
// W1[e][k][n] fp32 -> W1t[e][n][k] bf16 ; W2[e][h][o] fp32 -> W2t[e][o][h] bf16
// ---------------------------------------------------------------------------
__global__ __launch_bounds__(256) void convert_weights_kernel(
    const float* __restrict__ W1, const float* __restrict__ W2,
    __hip_bfloat16* __restrict__ W1t, __hip_bfloat16* __restrict__ W2t)
{
  __shared__ float tile[32][33];
  const int z = blockIdx.z;
  const float* src = (z & 8) ? W2 : W1;
  __hip_bfloat16* dst = (z & 8) ? W2t : W1t;
  const int e = z & 7;
  src += (size_t)e * 1024 * 1024;
  dst += (size_t)e * 1024 * 1024;
  const int R = blockIdx.y * 32, C = blockIdx.x * 32;
  const int c = threadIdx.x & 31, r0 = threadIdx.x >> 5;
#pragma unroll
  for (int p = 0; p < 4; p++) {
    const int r = r0 + p * 8;
    tile[r][c] = src[(size_t)(R + r) * 1024 + C + c];
  }
  __syncthreads();
#pragma unroll
  for (int p = 0; p < 4; p++) {
    const int r = r0 + p * 8;
    dst[(size_t)(C + r) * 1024 + R + c] = __float2bfloat16(tile[c][r]);
  }
}

// ---------------------------------------------------------------------------
// Compacted per-expert GEMM, m97 structure (128x128, BK=32), grid z = expert.
// MODE 0 (FC1): A = gather(x_bf, idx[e]);  hpool[e] = bf16(relu(A W1t^T + b1))
// MODE 1 (FC2): A = hpool[e];  out[idx[e][m]] += sw * (A W2t^T + b2)  (atomic)
// Row-blocks beyond cnt[e] exit immediately.
// ---------------------------------------------------------------------------
template <int MODE>
__global__ __launch_bounds__(256, 2) void moe_gemm(
    const __hip_bfloat16* __restrict__ x_bf,
    __hip_bfloat16* __restrict__ hpool,
    const __hip_bfloat16* __restrict__ Wt,
    const float* __restrict__ biasAll,
    const float* __restrict__ sw,
    const int* __restrict__ idx, const int* __restrict__ cnt,
    float* __restrict__ out)
{
  const int e = blockIdx.z;
  const int count = cnt[e];
  const int m0 = blockIdx.y * 128;
  if (m0 >= count) return;
  const int n0 = blockIdx.x * 128;

  __shared__ __align__(16) __hip_bfloat16 sA[128 * 32];
  __shared__ __align__(16) __hip_bfloat16 sB[128 * 32];
  const int t = threadIdx.x;
  const int lane = t & 63;
  const int wave = t >> 6;
  const int wm = (wave & 1) * 64;
  const int wn = (wave >> 1) * 64;
  const int* idx_e = idx + e * N_TOK;
  const float* bias = biasAll + e * 1024;

  floatx4 acc[4][4];
#pragma unroll
  for (int i = 0; i < 4; i++)
#pragma unroll
    for (int j = 0; j < 4; j++) acc[i][j] = (floatx4){0.f, 0.f, 0.f, 0.f};

  // staging addresses: thread t loads 16B for rows sr and sr+64
  const int sr = t >> 2;
  const int sc = (t & 3) * 8;
  const __hip_bfloat16* Ag0;
  const __hip_bfloat16* Ag1;
  if (MODE == 0) {
    const int t0 = idx_e[min(m0 + sr, count - 1)];       // clamp tail (valid rows)
    const int t1 = idx_e[min(m0 + sr + 64, count - 1)];
    Ag0 = x_bf + (size_t)t0 * 1024 + sc;
    Ag1 = x_bf + (size_t)t1 * 1024 + sc;
  } else {
    const __hip_bfloat16* hp = hpool + (size_t)e * N_TOK * 1024;
    Ag0 = hp + (size_t)(m0 + sr) * 1024 + sc;            // tail reads scratch: finite
    Ag1 = hp + (size_t)(m0 + sr + 64) * 1024 + sc;
  }
  const __hip_bfloat16* Bg = Wt + (size_t)e * 1024 * 1024 + (size_t)(n0 + sr) * 1024 + sc;
  __hip_bfloat16* lA = &sA[sr * 32 + sc];
  __hip_bfloat16* lB = &sB[sr * 32 + sc];

  const int rf = lane & 15;
  const int k8 = (lane >> 4) * 8;
  const __hip_bfloat16* sAr = &sA[(wm + rf) * 32 + k8];
  const __hip_bfloat16* sBr = &sB[(wn + rf) * 32 + k8];

  for (int k0 = 0; k0 < 1024; k0 += 32) {
    async_load16(Ag0 + k0, lA);
    async_load16(Ag1 + k0, lA + 64 * 32);
    async_load16(Bg + k0, lB);
    async_load16(Bg + (size_t)64 * 1024 + k0, lB + 64 * 32);
    __syncthreads();
    short8 aF[4], bF[4];
#pragma unroll
    for (int i = 0; i < 4; i++) aF[i] = *(const short8*)(sAr + i * 16 * 32);
#pragma unroll
    for (int j = 0; j < 4; j++) bF[j] = *(const short8*)(sBr + j * 16 * 32);
#pragma unroll
    for (int i = 0; i < 4; i++)
#pragma unroll
      for (int j = 0; j < 4; j++)
        acc[i][j] = __builtin_amdgcn_mfma_f32_16x16x32_bf16(aF[i], bF[j], acc[i][j], 0, 0, 0);
    __syncthreads();
  }

  // epilogue: C/D layout col = lane&15, row = (lane>>4)*4 + reg
  const int quad = lane >> 4;
  const int cn = lane & 15;
#pragma unroll
  for (int i = 0; i < 4; i++) {
#pragma unroll
    for (int r = 0; r < 4; r++) {
      const int gm = m0 + wm + i * 16 + quad * 4 + r;
      if (gm >= count) continue;
      int tok = 0; float swv = 0.f;
      if (MODE == 1) {
        tok = idx_e[gm];
        swv = sw[tok * 8 + e];
      }
#pragma unroll
      for (int j = 0; j < 4; j++) {
        const int gn = n0 + wn + j * 16 + cn;
        const float v = acc[i][j][r] + bias[gn];
        if (MODE == 0) {
          hpool[((size_t)e * N_TOK + gm) * 1024 + gn] = __float2bfloat16(fmaxf(v, 0.f));
        } else {
          unsafeAtomicAdd(&out[(size_t)tok * 1024 + gn], swv * v);
        }
      }
    }
  }
}

// ---------------------------------------------------------------------------
extern "C" void kernel_launch(void* const* d_in, const int* in_sizes, int n_in,
                              void* d_out, int out_size, void* d_ws, size_t ws_size,
                              hipStream_t stream) {
  const float* x    = (const float*)d_in[0];
  const float* Wsel = (const float*)d_in[1];
  const float* bsel = (const float*)d_in[2];
  const float* W1   = (const float*)d_in[3];
  const float* b1   = (const float*)d_in[4];
  const float* W2   = (const float*)d_in[5];
  const float* b2   = (const float*)d_in[6];
  float* out = (float*)d_out;

  char* ws = (char*)d_ws;
  __hip_bfloat16* x_bf = (__hip_bfloat16*)ws; ws += (size_t)N_TOK * DIN * 2;
  __hip_bfloat16* W1t  = (__hip_bfloat16*)ws; ws += (size_t)NE * DIN * HID * 2;
  __hip_bfloat16* W2t  = (__hip_bfloat16*)ws; ws += (size_t)NE * HID * DOUT * 2;
  float* sw            = (float*)ws;          ws += (size_t)N_TOK * NE * 4;
  int* idx             = (int*)ws;            ws += (size_t)NE * N_TOK * 4;
  int* cnt             = (int*)ws;            ws += 256;
  __hip_bfloat16* hpool = (__hip_bfloat16*)ws;  // NE*N_TOK*HID*2 = 134 MB

  zero_kernel<<<1024, 256, 0, stream>>>((float4*)out, N_TOK * DOUT / 4);
  selector_kernel<<<N_TOK / 4, 256, 0, stream>>>(x, Wsel, bsel, x_bf, sw);
  compact_kernel<<<NE, 1024, 0, stream>>>(sw, idx, cnt);
  convert_weights_kernel<<<dim3(32, 32, 16), 256, 0, stream>>>(W1, W2, W1t, W2t);

  moe_gemm<0><<<dim3(HID / 128, N_TOK / 128, NE), 256, 0, stream>>>(
      x_bf, hpool, W1t, b1, sw, idx, cnt, out);
  moe_gemm<1><<<dim3(DOUT / 128, N_TOK / 128, NE), 256, 0, stream>>>(
      x_bf, hpool, W2t, b2, sw, idx, cnt, out);
}